// Round 10
// baseline (94.399 us; speedup 1.0000x reference)
//
#include <hip/hip_runtime.h>

#define NUM_SEG 256
#define WAY 2
#define NCH 128
#define CHB 64                       // channels per block (ch-split)
#define HW 65536                     // 256*256
#define N_IMG 8
#define PIX_PER_BLK 2048
#define CHUNKS_PER_IMG 32
#define NTHREADS 1024
#define TOTAL_SEG (N_IMG * NUM_SEG)  // 2048
#define NPART (N_IMG * CHUNKS_PER_IMG)     // 256 partial tiles
#define NBLOCKS (NPART * 2)          // 512 blocks, 2 per CU
#define PART_ELEMS (NUM_SEG * NCH)   // 32768
#define KW 32                        // pixels per K-chunk
#define NITER (PIX_PER_BLK / KW)     // 64
#define LDR 40                       // padded At row, shorts (80 B)
#define SSTR 68                      // strip stride, floats (272 B, 16B-aligned)

typedef __attribute__((ext_vector_type(8))) short short8;
typedef __attribute__((ext_vector_type(2))) short short2v;
typedef __attribute__((ext_vector_type(4))) float f32x4;

static __device__ __forceinline__ unsigned short f2bf(float f) {
    unsigned int u = __float_as_uint(f);
    unsigned int r = u + 0x7FFFu + ((u >> 16) & 1u);
    return (unsigned short)(r >> 16);
}

static __device__ __forceinline__ short2v cvt2(float2 v) {
    short2v r;
    r[0] = (short)f2bf(v.x); r[1] = (short)f2bf(v.y);
    return r;
}

// One-hot MFMA segment-sum; B-fragments built in VALU from segb (no OH tile,
// no scatter machinery). r8 control flow otherwise: ch-split, dbuf At,
// plain __syncthreads, 2 blocks/CU, 32 waves/CU.
__global__ __launch_bounds__(NTHREADS, 8)
void seg_mfma_kernel(const float* __restrict__ img,
                     const int* __restrict__ mask,
                     const int* __restrict__ segs,
                     float* __restrict__ ws_part,      // [NPART][256 seg][128 ch]
                     int* __restrict__ labcnt_g) {     // [TOTAL_SEG][WAY]
    __shared__ __align__(16) unsigned short At[2][CHB][LDR];   // 10 KB bf16 A
    __shared__ __align__(8) unsigned char segb[PIX_PER_BLK];   // 2 KB
    __shared__ int labc[NUM_SEG * WAY];                        // 2 KB
    __shared__ __align__(16) float strip[8 * 16 * SSTR];       // 34 KB epilogue
    // ~48 KB -> 2 blocks/CU (wave-limited)

    const int bid   = blockIdx.x;        // n*64 + chunk*2 + h
    const int h     = bid & 1;
    const int chunk = (bid >> 1) & 31;
    const int n     = bid >> 6;
    const int t     = threadIdx.x;
    const int lane  = t & 63;
    const int w     = t >> 6;            // wave 0..15
    const int mg    = w & 1;             // ch-local tile base 32*mg
    const int ng    = w >> 1;            // seg group base 32*ng
    const int l15   = lane & 15;
    const int hi4   = lane >> 4;
    const int kA    = 8 * hi4;

    const long pixbase = (long)n * HW + chunk * PIX_PER_BLK;

    if (h == 0)
        for (int i = t; i < NUM_SEG * WAY; i += NTHREADS) labc[i] = 0;
    __syncthreads();

    // stage seg ids (u8); h==0 blocks also build the label histogram
    for (int p = t; p < PIX_PER_BLK; p += NTHREADS) {
        int s = segs[pixbase + p];
        segb[p] = (unsigned char)s;
        if (h == 0) atomicAdd(&labc[s * 2 + mask[pixbase + p]], 1);
    }

    // A staging: 16 threads/row, float2 each (32 px/chunk, 128 B/row contiguous)
    const int arow = t >> 4;             // 0..63
    const int acol = (t & 15) * 2;       // 0..30
    const float* gA = img + (long)(n * NCH + h * CHB + arow) * HW
                          + chunk * PIX_PER_BLK + acol;

    // load chunk 0
    float2 fc = *(const float2*)(gA);
    __syncthreads();                      // segb visible

    // build chunk 0 into At[0]
    *(short2v*)&At[0][arow][acol] = cvt2(fc);
    fc = *(const float2*)(gA + KW);       // issue load chunk 1
    __syncthreads();                      // At[0] visible

    f32x4 acc[2][2] = {};
    const int tgt0 = 32 * ng + l15;       // this lane's seg for nj=0
    const int tgt1 = tgt0 + 16;           // and nj=1
    const short one = (short)0x3F80;      // bf16 1.0

    for (int it = 0; it < NITER; ++it) {
        const int cur = it & 1, nxt = cur ^ 1;

        // issue load for chunk it+2 (consumed next iteration)
        float2 fn = fc;
        if (it + 2 < NITER) fn = *(const float2*)(gA + (it + 2) * KW);

        // build both B-fragments in VALU from segb (broadcast 8-byte read)
        uint2 sw = *(const uint2*)&segb[it * KW + kA];
        short8 b0, b1;
        #pragma unroll
        for (int j = 0; j < 4; ++j) {
            int s0 = (sw.x >> (8 * j)) & 255;
            int s1 = (sw.y >> (8 * j)) & 255;
            b0[j]     = (s0 == tgt0) ? one : (short)0;
            b0[j + 4] = (s1 == tgt0) ? one : (short)0;
            b1[j]     = (s0 == tgt1) ? one : (short)0;
            b1[j + 4] = (s1 == tgt1) ? one : (short)0;
        }

        // A-frags from LDS + 4 MFMAs
        short8 a0 = *(const short8*)&At[cur][32 * mg      + l15][kA];
        short8 a1 = *(const short8*)&At[cur][32 * mg + 16 + l15][kA];
        acc[0][0] = __builtin_amdgcn_mfma_f32_16x16x32_bf16(a0, b0, acc[0][0], 0, 0, 0);
        acc[1][0] = __builtin_amdgcn_mfma_f32_16x16x32_bf16(a1, b0, acc[1][0], 0, 0, 0);
        acc[0][1] = __builtin_amdgcn_mfma_f32_16x16x32_bf16(a0, b1, acc[0][1], 0, 0, 0);
        acc[1][1] = __builtin_amdgcn_mfma_f32_16x16x32_bf16(a1, b1, acc[1][1], 0, 0, 0);

        // stage chunk it+1 into nxt buffer (disjoint from cur)
        if (it + 1 < NITER)
            *(short2v*)&At[nxt][arow][acol] = cvt2(fc);
        __syncthreads();
        fc = fn;
    }

    // epilogue: strip [8 ng][16 seg][SSTR] fp32, 2 rounds (nj=0,1)
    float* wsb = ws_part + (long)(n * CHUNKS_PER_IMG + chunk) * PART_ELEMS;
    #pragma unroll
    for (int nj = 0; nj < 2; ++nj) {
        // D layout: col(seg-local)=l15, row(ch-local)=4*hi4+r
        #pragma unroll
        for (int m = 0; m < 2; ++m)
            #pragma unroll
            for (int r = 0; r < 4; ++r)
                strip[(ng * 16 + l15) * SSTR + 32 * mg + 16 * m + 4 * hi4 + r] =
                    (nj == 0) ? acc[m][0][r] : acc[m][1][r];
        __syncthreads();
        {   // copy 128 rows x 64 floats: 8 threads/row, 8 floats each
            const int row = t >> 3;          // ng = row>>4, sl = row&15
            const int off = (t & 7) * 8;
            const float4* src = (const float4*)&strip[row * SSTR + off];
            float4 v0 = src[0], v1 = src[1];
            const int sgid = 32 * (row >> 4) + 16 * nj + (row & 15);
            float* dst = wsb + (long)sgid * NCH + h * CHB + off;
            ((float4*)dst)[0] = v0;
            ((float4*)dst)[1] = v1;
        }
        __syncthreads();
    }

    if (h == 0)
        for (int i = t; i < NUM_SEG * WAY; i += NTHREADS)
            atomicAdd(&labcnt_g[n * NUM_SEG * WAY + i], labc[i]);
}

// sum 32 chunk-partials, divide by count, emit labels
__global__ void reduce_ws_kernel(const float* __restrict__ ws_part,
                                 const int* __restrict__ labcnt,
                                 float* __restrict__ out) {
    const int nmean = TOTAL_SEG * NCH;    // 262144
    int i = blockIdx.x * blockDim.x + threadIdx.x;
    if (i < nmean) {
        int nimg = i >> 15;               // / 32768
        int rem  = i & 32767;             // s*128 + c
        const float* base = ws_part + (long)nimg * 32 * PART_ELEMS + rem;
        float acc = 0.0f;
        #pragma unroll
        for (int j = 0; j < CHUNKS_PER_IMG; ++j)
            acc += base[(long)j * PART_ELEMS];
        int g  = i >> 7;                  // n*256 + s
        int c0 = labcnt[g * 2 + 0];
        int c1 = labcnt[g * 2 + 1];
        out[i] = acc / fmaxf((float)(c0 + c1), 1.0f);
    } else if (i < nmean + TOTAL_SEG) {
        int g = i - nmean;
        out[i] = (labcnt[g * 2 + 1] > labcnt[g * 2 + 0]) ? 1.0f : 0.0f;
    }
}

extern "C" void kernel_launch(void* const* d_in, const int* in_sizes, int n_in,
                              void* d_out, int out_size, void* d_ws, size_t ws_size,
                              hipStream_t stream) {
    const float* img  = (const float*)d_in[0];   // (8,128,256,256) f32
    const int*   mask = (const int*)d_in[1];     // (8,256,256) i32 in [0,2)
    const int*   segs = (const int*)d_in[2];     // (8,256,256) i32 in [0,256)

    float* out = (float*)d_out;

    const size_t part_bytes = (size_t)NPART * PART_ELEMS * sizeof(float); // 32 MB
    float* ws_part = (float*)d_ws;
    int*   labcnt  = (int*)((char*)d_ws + part_bytes);

    hipMemsetAsync(labcnt, 0, (size_t)TOTAL_SEG * WAY * sizeof(int), stream);

    seg_mfma_kernel<<<NBLOCKS, NTHREADS, 0, stream>>>(
        img, mask, segs, ws_part, labcnt);

    const int totalThreads = TOTAL_SEG * NCH + TOTAL_SEG;   // 264192
    reduce_ws_kernel<<<(totalThreads + 255) / 256, 256, 0, stream>>>(
        ws_part, labcnt, out);
}

// Round 11
// 82.598 us; speedup vs baseline: 1.1429x; 1.1429x over previous
//
#include <hip/hip_runtime.h>

#define NUM_SEG 256
#define WAY 2
#define NCH 128
#define CHB 64                       // channels per block (ch-split)
#define HW 65536                     // 256*256
#define N_IMG 8
#define PIX_PER_BLK 2048
#define CHUNKS_PER_IMG 32
#define NTHREADS 1024
#define TOTAL_SEG (N_IMG * NUM_SEG)  // 2048
#define NPART (N_IMG * CHUNKS_PER_IMG)     // 256 partial tiles
#define NBLOCKS (NPART * 2)          // 512 blocks, 2 per CU
#define PART_ELEMS (NUM_SEG * NCH)   // 32768
#define KW 32                        // pixels per K-chunk
#define NITER (PIX_PER_BLK / KW)     // 64
#define LDR 40                       // padded row, shorts (80 B, 16B-aligned)
#define SSTR 68                      // strip stride, floats (272 B)

typedef __attribute__((ext_vector_type(8))) short short8;
typedef __attribute__((ext_vector_type(2))) short short2v;
typedef __attribute__((ext_vector_type(16))) float f32x16;

static __device__ __forceinline__ unsigned short f2bf(float f) {
    unsigned int u = __float_as_uint(f);
    unsigned int r = u + 0x7FFFu + ((u >> 16) & 1u);
    return (unsigned short)(r >> 16);
}

static __device__ __forceinline__ short2v cvt2(float2 v) {
    short2v r;
    r[0] = (short)f2bf(v.x); r[1] = (short)f2bf(v.y);
    return r;
}

// One-hot MFMA segment-sum, r8 control flow, 32x32x16 MFMA + k-split waves.
// Block (n, chunk, h): C[ch in h*64..h*64+64)][seg] over 2048 px.
// 16 waves = kg(2) x mg(2) x ng(4); wave: 32ch x 64seg x k-half.
// Per wave-iter: 3 ds_read_b128 -> 2 MFMA (32x32x16) = 0.75 reads/tile-op.
__global__ __launch_bounds__(NTHREADS, 8)
void seg_mfma_kernel(const float* __restrict__ img,
                     const int* __restrict__ mask,
                     const int* __restrict__ segs,
                     float* __restrict__ ws_part,      // [NPART][256 seg][128 ch]
                     int* __restrict__ labcnt_g) {     // [TOTAL_SEG][WAY]
    __shared__ __align__(16) unsigned short OH[2][NUM_SEG][LDR]; // 40 KB one-hot B
    __shared__ __align__(16) unsigned short At[2][CHB][LDR];     // 10 KB bf16 A
    __shared__ unsigned char segb[PIX_PER_BLK];                  // 2 KB
    __shared__ int labc[NUM_SEG * WAY];                          // 2 KB
    // 54 KB -> 2 blocks/CU

    const int bid   = blockIdx.x;        // n*64 + chunk*2 + h
    const int h     = bid & 1;
    const int chunk = (bid >> 1) & 31;
    const int n     = bid >> 6;
    const int t     = threadIdx.x;
    const int lane  = t & 63;
    const int w     = t >> 6;            // wave 0..15
    const int kg    = w & 1;             // k-half: k in [16*kg, 16*kg+16)
    const int mg    = (w >> 1) & 1;      // ch tile base 32*mg
    const int ng    = w >> 2;            // seg group base 64*ng
    const int l31   = lane & 31;
    const int h5    = lane >> 5;         // 0/1
    const int kc    = 16 * kg + 8 * h5;  // column (short index) of this lane's 8 k's

    const long pixbase = (long)n * HW + chunk * PIX_PER_BLK;

    // zero OH (both buffers incl. pads) + labc
    {
        int4 z; z.x = z.y = z.z = z.w = 0;
        int4* p = (int4*)&OH[0][0][0];
        for (int i = t; i < (2 * NUM_SEG * LDR * 2) / 16; i += NTHREADS) p[i] = z;
        if (h == 0)
            for (int i = t; i < NUM_SEG * WAY; i += NTHREADS) labc[i] = 0;
    }
    __syncthreads();

    // stage seg ids (u8); h==0 blocks also build the label histogram
    for (int p = t; p < PIX_PER_BLK; p += NTHREADS) {
        int s = segs[pixbase + p];
        segb[p] = (unsigned char)s;
        if (h == 0) atomicAdd(&labc[s * 2 + mask[pixbase + p]], 1);
    }

    // A staging: 16 threads/row, float2 each (32 px/chunk, 128 B/row contiguous)
    const int arow = t >> 4;             // 0..63
    const int acol = (t & 15) * 2;       // 0..30
    const float* gA = img + (long)(n * NCH + h * CHB + arow) * HW
                          + chunk * PIX_PER_BLK + acol;

    // load chunk 0
    float2 fc = *(const float2*)(gA);
    __syncthreads();                      // segb + OH zeros visible

    // build chunk 0 into At[0], OH[0]
    *(short2v*)&At[0][arow][acol] = cvt2(fc);
    const bool sc = (t < KW);             // wave-0 lanes 0..31 own one-hot cols
    int s_prev = -1, s_cur = -1;
    if (sc) {
        s_cur = segb[t];
        OH[0][s_cur][t] = 0x3F80;         // bf16 1.0
    }
    fc = *(const float2*)(gA + KW);       // issue load chunk 1
    __syncthreads();                      // At[0], OH[0] visible

    f32x16 acc0 = {};                     // segs 64*ng +  0..31
    f32x16 acc1 = {};                     // segs 64*ng + 32..63

    for (int it = 0; it < NITER; ++it) {
        const int cur = it & 1, nxt = cur ^ 1;

        // issue load for chunk it+2 (consumed next iteration)
        float2 fn = fc;
        if (it + 2 < NITER) fn = *(const float2*)(gA + (it + 2) * KW);
        int s_next = 0;
        if (sc && it + 1 < NITER) s_next = segb[(it + 1) * KW + t];

        // MFMA on chunk it: 1 A-frag + 2 B-frags -> 2 MFMAs (32x32x16)
        // A: row(ch)=l31, k=kc+j ; B: col(seg)=l31, k=kc+j
        short8 a  = *(const short8*)&At[cur][32 * mg + l31][kc];
        short8 b0 = *(const short8*)&OH[cur][64 * ng      + l31][kc];
        short8 b1 = *(const short8*)&OH[cur][64 * ng + 32 + l31][kc];
        acc0 = __builtin_amdgcn_mfma_f32_32x32x16_bf16(a, b0, acc0, 0, 0, 0);
        acc1 = __builtin_amdgcn_mfma_f32_32x32x16_bf16(a, b1, acc1, 0, 0, 0);

        // stage chunk it+1 into nxt buffers (disjoint from cur)
        if (it + 1 < NITER) {
            *(short2v*)&At[nxt][arow][acol] = cvt2(fc);
            if (sc) {
                if (s_prev >= 0 && s_prev != s_next) OH[nxt][s_prev][t] = 0;
                OH[nxt][s_next][t] = 0x3F80;
                s_prev = s_cur;
                s_cur  = s_next;
            }
        }
        __syncthreads();
        fc = fn;
    }

    // epilogue: strip[2 kg][64 seg][SSTR] fp32 (34.8 KB, reuse OH), 4 rounds.
    // D layout: col(seg-local)=l31, row(ch-local)=(reg&3)+8*(reg>>2)+4*h5.
    float* strip = (float*)&OH[0][0][0];
    float* wsb = ws_part + (long)(n * CHUNKS_PER_IMG + chunk) * PART_ELEMS;
    for (int ngp = 0; ngp < 4; ++ngp) {
        if (ng == ngp) {
            #pragma unroll
            for (int nj = 0; nj < 2; ++nj) {
                #pragma unroll
                for (int q = 0; q < 4; ++q) {
                    float4 v;
                    if (nj == 0) {
                        v.x = acc0[4 * q + 0]; v.y = acc0[4 * q + 1];
                        v.z = acc0[4 * q + 2]; v.w = acc0[4 * q + 3];
                    } else {
                        v.x = acc1[4 * q + 0]; v.y = acc1[4 * q + 1];
                        v.z = acc1[4 * q + 2]; v.w = acc1[4 * q + 3];
                    }
                    // ch-local rows 8q+4h5 .. +3 (reg&3 consecutive)
                    const int idx = (kg * 64 + 32 * nj + l31) * SSTR
                                  + 32 * mg + 8 * q + 4 * h5;
                    *(float4*)&strip[idx] = v;
                }
            }
        }
        __syncthreads();
        {   // copy-out with kg-reduce: row = seg-local, 16 thr/row x float4
            const int row = t >> 4;          // 0..63
            const int off = (t & 15) * 4;    // 0..60
            float4 va = *(const float4*)&strip[row * SSTR + off];
            float4 vb = *(const float4*)&strip[(64 + row) * SSTR + off];
            float4 o; o.x = va.x + vb.x; o.y = va.y + vb.y;
            o.z = va.z + vb.z; o.w = va.w + vb.w;
            float* dst = wsb + (long)(64 * ngp + row) * NCH + h * CHB + off;
            *(float4*)dst = o;
        }
        __syncthreads();
    }

    if (h == 0)
        for (int i = t; i < NUM_SEG * WAY; i += NTHREADS)
            atomicAdd(&labcnt_g[n * NUM_SEG * WAY + i], labc[i]);
}

// sum 32 chunk-partials, divide by count, emit labels
__global__ void reduce_ws_kernel(const float* __restrict__ ws_part,
                                 const int* __restrict__ labcnt,
                                 float* __restrict__ out) {
    const int nmean = TOTAL_SEG * NCH;    // 262144
    int i = blockIdx.x * blockDim.x + threadIdx.x;
    if (i < nmean) {
        int nimg = i >> 15;               // / 32768
        int rem  = i & 32767;             // s*128 + c
        const float* base = ws_part + (long)nimg * 32 * PART_ELEMS + rem;
        float acc = 0.0f;
        #pragma unroll
        for (int j = 0; j < CHUNKS_PER_IMG; ++j)
            acc += base[(long)j * PART_ELEMS];
        int g  = i >> 7;                  // n*256 + s
        int c0 = labcnt[g * 2 + 0];
        int c1 = labcnt[g * 2 + 1];
        out[i] = acc / fmaxf((float)(c0 + c1), 1.0f);
    } else if (i < nmean + TOTAL_SEG) {
        int g = i - nmean;
        out[i] = (labcnt[g * 2 + 1] > labcnt[g * 2 + 0]) ? 1.0f : 0.0f;
    }
}

extern "C" void kernel_launch(void* const* d_in, const int* in_sizes, int n_in,
                              void* d_out, int out_size, void* d_ws, size_t ws_size,
                              hipStream_t stream) {
    const float* img  = (const float*)d_in[0];   // (8,128,256,256) f32
    const int*   mask = (const int*)d_in[1];     // (8,256,256) i32 in [0,2)
    const int*   segs = (const int*)d_in[2];     // (8,256,256) i32 in [0,256)

    float* out = (float*)d_out;

    const size_t part_bytes = (size_t)NPART * PART_ELEMS * sizeof(float); // 32 MB
    float* ws_part = (float*)d_ws;
    int*   labcnt  = (int*)((char*)d_ws + part_bytes);

    hipMemsetAsync(labcnt, 0, (size_t)TOTAL_SEG * WAY * sizeof(int), stream);

    seg_mfma_kernel<<<NBLOCKS, NTHREADS, 0, stream>>>(
        img, mask, segs, ws_part, labcnt);

    const int totalThreads = TOTAL_SEG * NCH + TOTAL_SEG;   // 264192
    reduce_ws_kernel<<<(totalThreads + 255) / 256, 256, 0, stream>>>(
        ws_part, labcnt, out);
}